// Round 5
// baseline (176.198 us; speedup 1.0000x reference)
//
#include <hip/hip_runtime.h>

#define NVOX 120000
#define KVOL 27
#define CH 64
#define TOTAL (NVOX * CH)
#define EPSV 1e-5f

typedef __attribute__((ext_vector_type(8))) short bf16x8;
typedef __attribute__((ext_vector_type(4))) float f32x4;
typedef __attribute__((ext_vector_type(4))) unsigned int u32x4;

__device__ __forceinline__ unsigned short f2bf(float f) {
    unsigned int u = __builtin_bit_cast(unsigned int, f);
    u += 0x7FFFu + ((u >> 16) & 1u);          // RNE
    return (unsigned short)(u >> 16);
}

// ---- prep ------------------------------------------------------------------
// blocks [0,432): weight fp32 [k][c][d] -> bf16 in MFMA-fragment order:
//   chunk(k, grp, lane) holds W[k][c = (grp&1)*32 + (lane>>4)*8 + j][d = (grp>>1)*16 + (lane&15)]
//   stored at wtf[((k*8 + grp)*64 + lane)*8 + j]  (16B chunks, lane-contiguous)
// blocks [432, 432+7500): feats fp32 -> bf16 (coalesced float4)
__global__ void prep(const float* __restrict__ w, unsigned short* __restrict__ wtf,
                     const float* __restrict__ f, unsigned short* __restrict__ fb,
                     float* __restrict__ stats) {
    const int b = blockIdx.x;
    const int tid = threadIdx.x;
    if (b < 432) {
        const int t = b * 256 + tid;               // t = k*4096 + c*64 + d (coalesced read)
        const int d = t & 63, c = (t >> 6) & 63, k = t >> 12;
        const int grp = (d >> 4) * 2 + (c >> 5);
        const int l = ((c & 31) >> 3) * 16 + (d & 15);
        const int j = c & 7;
        wtf[(((size_t)k * 8 + grp) * 64 + l) * 8 + j] = f2bf(w[t]);
        if (b == 0 && tid < 128) stats[tid] = 0.f;
    } else {
        const int t = (b - 432) * 256 + tid;       // float4 index, 1,920,000 total
        const float4 x = ((const float4*)f)[t];
        ushort4 y;
        y.x = f2bf(x.x); y.y = f2bf(x.y); y.z = f2bf(x.z); y.w = f2bf(x.w);
        ((ushort4*)fb)[t] = y;
    }
}

__device__ __forceinline__ void gatherRow(const unsigned short* __restrict__ fb,
                                          int idx, int q, bf16x8& a0, bf16x8& a1) {
    const int safe = idx < 0 ? 0 : idx;
    const unsigned short* row = fb + (size_t)safe * CH + q * 8;
    a0 = *(const bf16x8*)row;
    a1 = *(const bf16x8*)(row + 32);
    if (idx < 0) {
        a0 = (bf16x8)(short)0;
        a1 = (bf16x8)(short)0;
    }
}

// ---- conv: 64 voxels/block, 1875 blocks, frag-ordered LDS weights ----------
// launch_bounds(256,4): <=128 unified VGPR+AGPR. (256,8) strangled the
// allocator to 32 VGPRs -> pipeline state demoted, 10x serialization (round 4).
__launch_bounds__(256, 4)
__global__ void conv_mfma(const unsigned short* __restrict__ featsB,
                          const unsigned short* __restrict__ WtF,
                          const int* __restrict__ nbr,
                          float* __restrict__ out,
                          float* __restrict__ stats) {
    __shared__ __align__(16) unsigned short ldsW[2][4096];   // 2 x 8KB, frag order
    __shared__ float lstats[128];
    const int tid = threadIdx.x;
    const int lane = tid & 63;
    const int wave = tid >> 6;
    const int m = lane & 15;
    const int q = lane >> 4;
    const int v0 = blockIdx.x * 64 + wave * 16;

    const int c0 = tid, c1 = tid + 256;            // staging chunk ids (16B each)

    // prologue: stage W[0], prefetch W[1] into regs, start A pipeline
    u32x4 wr0 = *(const u32x4*)(WtF + (size_t)c0 * 8);
    u32x4 wr1 = *(const u32x4*)(WtF + (size_t)c1 * 8);
    *(u32x4*)(&ldsW[0][c0 * 8]) = wr0;
    *(u32x4*)(&ldsW[0][c1 * 8]) = wr1;
    wr0 = *(const u32x4*)(WtF + 4096 + (size_t)c0 * 8);
    wr1 = *(const u32x4*)(WtF + 4096 + (size_t)c1 * 8);

    bf16x8 a0, a1;
    gatherRow(featsB, nbr[v0 + m], q, a0, a1);
    int idx_nxt = nbr[NVOX + v0 + m];

    f32x4 acc[4];
#pragma unroll
    for (int nt = 0; nt < 4; ++nt) acc[nt] = (f32x4){0.f, 0.f, 0.f, 0.f};
    if (tid < 128) lstats[tid] = 0.f;
    __syncthreads();

    int bsel = 0;
    for (int k = 0; k < KVOL; ++k) {
        const unsigned short* bufR = &ldsW[bsel][0];
        unsigned short* bufW = &ldsW[bsel ^ 1][0];

        if (k + 1 < KVOL) {                         // stage W[k+1]
            *(u32x4*)(bufW + c0 * 8) = wr0;
            *(u32x4*)(bufW + c1 * 8) = wr1;
        }
        if (k + 2 < KVOL) {                         // prefetch W[k+2]
            wr0 = *(const u32x4*)(WtF + (size_t)(k + 2) * 4096 + c0 * 8);
            wr1 = *(const u32x4*)(WtF + (size_t)(k + 2) * 4096 + c1 * 8);
        }
        int idx_n2 = 0;
        if (k + 2 < KVOL) idx_n2 = nbr[(size_t)(k + 2) * NVOX + v0 + m];
        bf16x8 an0, an1;
        if (k + 1 < KVOL) gatherRow(featsB, idx_nxt, q, an0, an1);

        // compute: B frags lane-contiguous in LDS (conflict-free b128)
#pragma unroll
        for (int nt = 0; nt < 4; ++nt) {
            const bf16x8 b0 = *(const bf16x8*)(bufR + (nt * 2 + 0) * 512 + lane * 8);
            const bf16x8 b1 = *(const bf16x8*)(bufR + (nt * 2 + 1) * 512 + lane * 8);
            acc[nt] = __builtin_amdgcn_mfma_f32_16x16x32_bf16(a0, b0, acc[nt], 0, 0, 0);
            acc[nt] = __builtin_amdgcn_mfma_f32_16x16x32_bf16(a1, b1, acc[nt], 0, 0, 0);
        }

        if (k + 1 < KVOL) {
            a0 = an0; a1 = an1;
            idx_nxt = idx_n2;
            bsel ^= 1;
            __syncthreads();
        }
    }

    // ---- epilogue: stores + block-reduced BN statistics ----
    // D layout: col = m (channel nt*16+m), row = q*4 + r (voxel)
    float* ob = out + (size_t)(v0 + q * 4) * CH + m;
#pragma unroll
    for (int nt = 0; nt < 4; ++nt)
#pragma unroll
        for (int r = 0; r < 4; ++r)
            ob[(size_t)r * CH + nt * 16] = acc[nt][r];

#pragma unroll
    for (int nt = 0; nt < 4; ++nt) {
        float s = 0.f, s2 = 0.f;
#pragma unroll
        for (int r = 0; r < 4; ++r) {
            const float x = acc[nt][r];
            s += x;
            s2 = fmaf(x, x, s2);
        }
        s  += __shfl_xor(s, 16);  s  += __shfl_xor(s, 32);
        s2 += __shfl_xor(s2, 16); s2 += __shfl_xor(s2, 32);
        if (lane < 16) {
            atomicAdd(&lstats[nt * 16 + m], s);
            atomicAdd(&lstats[64 + nt * 16 + m], s2);
        }
    }
    __syncthreads();
    if (tid < 128) atomicAdd(&stats[tid], lstats[tid]);
}

// ---- bn_relu with inline finalize ------------------------------------------
__launch_bounds__(256)
__global__ void bn_relu(float* __restrict__ out, const float* __restrict__ stats,
                        const float* __restrict__ gamma, const float* __restrict__ beta) {
    __shared__ float sb[128];
    const int tid = threadIdx.x;
    if (tid < 64) {
        const float inv_n = 1.0f / (float)NVOX;
        const float mean = stats[tid] * inv_n;
        const float var = stats[64 + tid] * inv_n - mean * mean;
        const float sc = gamma[tid] * rsqrtf(var + EPSV);
        sb[tid] = sc;
        sb[64 + tid] = beta[tid] - mean * sc;
    }
    __syncthreads();
    const int e = blockIdx.x * 256 + tid;          // float4 index
    float4* o4 = (float4*)out;
    float4 x = o4[e];
    const int cb = (e & 15) * 4;
    x.x = fmaxf(fmaf(x.x, sb[cb + 0], sb[64 + cb + 0]), 0.f);
    x.y = fmaxf(fmaf(x.y, sb[cb + 1], sb[64 + cb + 1]), 0.f);
    x.z = fmaxf(fmaf(x.z, sb[cb + 2], sb[64 + cb + 2]), 0.f);
    x.w = fmaxf(fmaf(x.w, sb[cb + 3], sb[64 + cb + 3]), 0.f);
    o4[e] = x;
}

extern "C" void kernel_launch(void* const* d_in, const int* in_sizes, int n_in,
                              void* d_out, int out_size, void* d_ws, size_t ws_size,
                              hipStream_t stream) {
    const float* feats  = (const float*)d_in[0];   // [N, 64]
    const float* weight = (const float*)d_in[1];   // [27, 64, 64]
    const float* gamma  = (const float*)d_in[2];   // [64]
    const float* beta   = (const float*)d_in[3];   // [64]
    const int*   nbr    = (const int*)d_in[4];     // [27, N]
    float* out = (float*)d_out;                    // [N, 64]

    // ws layout: [0,512) stats; [512, 512+221184) WtF bf16 frag-order; then featsB
    float* stats = (float*)d_ws;
    unsigned short* WtF    = (unsigned short*)((char*)d_ws + 512);
    unsigned short* featsB = (unsigned short*)((char*)d_ws + 512 + 221184);

    prep<<<432 + TOTAL / 4 / 256, 256, 0, stream>>>(weight, WtF, feats, featsB, stats);
    conv_mfma<<<NVOX / 64, 256, 0, stream>>>(featsB, WtF, nbr, out, stats);
    bn_relu<<<TOTAL / 4 / 256, 256, 0, stream>>>(out, stats, gamma, beta);
}

// Round 7
// 167.054 us; speedup vs baseline: 1.0547x; 1.0547x over previous
//
#include <hip/hip_runtime.h>

#define NVOX 120000
#define KVOL 27
#define CH 64
#define TOTAL (NVOX * CH)
#define NF4 (TOTAL / 4)
#define EPSV 1e-5f
#define NPAIR 14   // 27 k-slices padded to 28, processed as 14 pairs

typedef __attribute__((ext_vector_type(8))) short bf16x8;
typedef __attribute__((ext_vector_type(4))) float f32x4;
typedef __attribute__((ext_vector_type(4))) unsigned int u32x4;

__device__ __forceinline__ unsigned short f2bf(float f) {
    unsigned int u = __builtin_bit_cast(unsigned int, f);
    u += 0x7FFFu + ((u >> 16) & 1u);          // RNE
    return (unsigned short)(u >> 16);
}

// ---- prep ------------------------------------------------------------------
// b <  432 : weight fp32 [k][c][d] -> bf16 MFMA-fragment order
//            wtf[((k*8 + grp)*64 + lane)*8 + j], grp=(d>>4)*2+(c>>5),
//            lane=((c&31)>>3)*16+(d&15), j=c&7
// b <  436 : zero-fill pad slice k=27 (4096 ushorts = 1024 ushort4 exactly;
//            round 6 used 8 blocks and overran into featsB -> corruption)
// b >= 436 : feats fp32 -> bf16, grid-stride float4
__global__ void prep(const float* __restrict__ w, unsigned short* __restrict__ wtf,
                     const float* __restrict__ f, unsigned short* __restrict__ fb,
                     float* __restrict__ stats) {
    const int b = blockIdx.x;
    const int tid = threadIdx.x;
    if (b < 432) {
        const int t = b * 256 + tid;               // t = k*4096 + c*64 + d (coalesced read)
        const int d = t & 63, c = (t >> 6) & 63, k = t >> 12;
        const int grp = (d >> 4) * 2 + (c >> 5);
        const int l = ((c & 31) >> 3) * 16 + (d & 15);
        const int j = c & 7;
        wtf[(((size_t)k * 8 + grp) * 64 + l) * 8 + j] = f2bf(w[t]);
        if (b == 0 && tid < 128) stats[tid] = 0.f;
    } else if (b < 436) {
        const int t = (b - 432) * 256 + tid;       // ushort4 index within pad slice
        ((ushort4*)(wtf + 27 * 4096))[t] = (ushort4){0, 0, 0, 0};
    } else {
        for (int t = (b - 436) * 256 + tid; t < NF4; t += 1000 * 256) {
            const float4 x = ((const float4*)f)[t];
            ushort4 y;
            y.x = f2bf(x.x); y.y = f2bf(x.y); y.z = f2bf(x.z); y.w = f2bf(x.w);
            ((ushort4*)fb)[t] = y;
        }
    }
}

__device__ __forceinline__ void gatherRow(const unsigned short* __restrict__ fb,
                                          int idx, int q, bf16x8& a0, bf16x8& a1) {
    const int safe = idx < 0 ? 0 : idx;
    const unsigned short* row = fb + (size_t)safe * CH + q * 8;
    a0 = *(const bf16x8*)row;
    a1 = *(const bf16x8*)(row + 32);
    if (idx < 0) {
        a0 = (bf16x8)(short)0;
        a1 = (bf16x8)(short)0;
    }
}

// ---- conv: 64 voxels/block, k-slices processed in PAIRS --------------------
// 13 barriers instead of 26; 16 MFMAs + 4 A-gathers + 4 W-loads per drain.
__launch_bounds__(256, 4)
__global__ void conv_mfma(const unsigned short* __restrict__ featsB,
                          const unsigned short* __restrict__ WtF,
                          const int* __restrict__ nbr,
                          float* __restrict__ out,
                          float* __restrict__ stats) {
    __shared__ __align__(16) unsigned short ldsW[2][8192];   // 2 bufs x (2 slices x 8KB)
    __shared__ float lstats[128];
    const int tid = threadIdx.x;
    const int lane = tid & 63;
    const int wave = tid >> 6;
    const int m = lane & 15;
    const int q = lane >> 4;
    const int v0 = blockIdx.x * 64 + wave * 16;

    // staging: 1024 x 16B chunks per pair; thread handles 4 chunks
    const int o0 = tid * 8, o1 = (tid + 256) * 8, o2 = (tid + 512) * 8, o3 = (tid + 768) * 8;

    // prologue: stage pair 0 directly, prefetch pair 1 into regs
    {
        u32x4 t0 = *(const u32x4*)(WtF + o0);
        u32x4 t1 = *(const u32x4*)(WtF + o1);
        u32x4 t2 = *(const u32x4*)(WtF + o2);
        u32x4 t3 = *(const u32x4*)(WtF + o3);
        *(u32x4*)(&ldsW[0][o0]) = t0;
        *(u32x4*)(&ldsW[0][o1]) = t1;
        *(u32x4*)(&ldsW[0][o2]) = t2;
        *(u32x4*)(&ldsW[0][o3]) = t3;
    }
    u32x4 wr0 = *(const u32x4*)(WtF + 8192 + o0);
    u32x4 wr1 = *(const u32x4*)(WtF + 8192 + o1);
    u32x4 wr2 = *(const u32x4*)(WtF + 8192 + o2);
    u32x4 wr3 = *(const u32x4*)(WtF + 8192 + o3);

    // A pipeline: current pair in a[], next-pair indices in j0/j1
    bf16x8 a[2][2];
    gatherRow(featsB, nbr[v0 + m], q, a[0][0], a[0][1]);
    gatherRow(featsB, nbr[NVOX + v0 + m], q, a[1][0], a[1][1]);
    int j0 = nbr[2 * NVOX + v0 + m];
    int j1 = nbr[3 * NVOX + v0 + m];

    f32x4 acc[4];
#pragma unroll
    for (int nt = 0; nt < 4; ++nt) acc[nt] = (f32x4){0.f, 0.f, 0.f, 0.f};
    if (tid < 128) lstats[tid] = 0.f;
    __syncthreads();

    int bsel = 0;
    for (int p = 0; p < NPAIR; ++p) {
        const unsigned short* bufR = &ldsW[bsel][0];
        unsigned short* bufW = &ldsW[bsel ^ 1][0];

        if (p + 1 < NPAIR) {                        // stage pair p+1 (regs -> LDS)
            *(u32x4*)(bufW + o0) = wr0;
            *(u32x4*)(bufW + o1) = wr1;
            *(u32x4*)(bufW + o2) = wr2;
            *(u32x4*)(bufW + o3) = wr3;
        }
        if (p + 2 < NPAIR) {                        // prefetch pair p+2
            const unsigned short* wp = WtF + (size_t)(p + 2) * 8192;
            wr0 = *(const u32x4*)(wp + o0);
            wr1 = *(const u32x4*)(wp + o1);
            wr2 = *(const u32x4*)(wp + o2);
            wr3 = *(const u32x4*)(wp + o3);
        }
        // prefetch indices for pair p+2 (slices 2p+4, 2p+5)
        int n0 = -1, n1 = -1;
        if (p + 2 < NPAIR) {
            n0 = nbr[(size_t)(2 * p + 4) * NVOX + v0 + m];
            n1 = (2 * p + 5 < KVOL) ? nbr[(size_t)(2 * p + 5) * NVOX + v0 + m] : -1;
        }
        // gather A for pair p+1
        bf16x8 an[2][2];
        if (p + 1 < NPAIR) {
            gatherRow(featsB, j0, q, an[0][0], an[0][1]);
            gatherRow(featsB, j1, q, an[1][0], an[1][1]);
        }

        // compute: 2 slices x 8 MFMAs, B frags lane-contiguous (conflict-free)
#pragma unroll
        for (int s = 0; s < 2; ++s) {
            const unsigned short* base = bufR + s * 4096;
#pragma unroll
            for (int nt = 0; nt < 4; ++nt) {
                const bf16x8 b0 = *(const bf16x8*)(base + (nt * 2 + 0) * 512 + lane * 8);
                const bf16x8 b1 = *(const bf16x8*)(base + (nt * 2 + 1) * 512 + lane * 8);
                acc[nt] = __builtin_amdgcn_mfma_f32_16x16x32_bf16(a[s][0], b0, acc[nt], 0, 0, 0);
                acc[nt] = __builtin_amdgcn_mfma_f32_16x16x32_bf16(a[s][1], b1, acc[nt], 0, 0, 0);
            }
        }

        if (p + 1 < NPAIR) {
#pragma unroll
            for (int s = 0; s < 2; ++s) {
                a[s][0] = an[s][0];
                a[s][1] = an[s][1];
            }
            j0 = n0; j1 = n1;
            bsel ^= 1;
            __syncthreads();
        }
    }

    // ---- epilogue: stores + block-reduced BN statistics ----
    // D layout: col = m (channel nt*16+m), row = q*4 + r (voxel)
    float* ob = out + (size_t)(v0 + q * 4) * CH + m;
#pragma unroll
    for (int nt = 0; nt < 4; ++nt)
#pragma unroll
        for (int r = 0; r < 4; ++r)
            ob[(size_t)r * CH + nt * 16] = acc[nt][r];

#pragma unroll
    for (int nt = 0; nt < 4; ++nt) {
        float s = 0.f, s2 = 0.f;
#pragma unroll
        for (int r = 0; r < 4; ++r) {
            const float x = acc[nt][r];
            s += x;
            s2 = fmaf(x, x, s2);
        }
        s  += __shfl_xor(s, 16);  s  += __shfl_xor(s, 32);
        s2 += __shfl_xor(s2, 16); s2 += __shfl_xor(s2, 32);
        if (lane < 16) {
            atomicAdd(&lstats[nt * 16 + m], s);
            atomicAdd(&lstats[64 + nt * 16 + m], s2);
        }
    }
    __syncthreads();
    if (tid < 128) atomicAdd(&stats[tid], lstats[tid]);
}

// ---- bn_relu: grid-stride with inline finalize -----------------------------
__launch_bounds__(256)
__global__ void bn_relu(float* __restrict__ out, const float* __restrict__ stats,
                        const float* __restrict__ gamma, const float* __restrict__ beta) {
    __shared__ float sb[128];
    const int tid = threadIdx.x;
    if (tid < 64) {
        const float inv_n = 1.0f / (float)NVOX;
        const float mean = stats[tid] * inv_n;
        const float var = stats[64 + tid] * inv_n - mean * mean;
        const float sc = gamma[tid] * rsqrtf(var + EPSV);
        sb[tid] = sc;
        sb[64 + tid] = beta[tid] - mean * sc;
    }
    __syncthreads();
    float4* o4 = (float4*)out;
    for (int e = blockIdx.x * 256 + tid; e < NF4; e += 960 * 256) {
        float4 x = o4[e];
        const int cb = (e & 15) * 4;
        x.x = fmaxf(fmaf(x.x, sb[cb + 0], sb[64 + cb + 0]), 0.f);
        x.y = fmaxf(fmaf(x.y, sb[cb + 1], sb[64 + cb + 1]), 0.f);
        x.z = fmaxf(fmaf(x.z, sb[cb + 2], sb[64 + cb + 2]), 0.f);
        x.w = fmaxf(fmaf(x.w, sb[cb + 3], sb[64 + cb + 3]), 0.f);
        o4[e] = x;
    }
}

extern "C" void kernel_launch(void* const* d_in, const int* in_sizes, int n_in,
                              void* d_out, int out_size, void* d_ws, size_t ws_size,
                              hipStream_t stream) {
    const float* feats  = (const float*)d_in[0];   // [N, 64]
    const float* weight = (const float*)d_in[1];   // [27, 64, 64]
    const float* gamma  = (const float*)d_in[2];   // [64]
    const float* beta   = (const float*)d_in[3];   // [64]
    const int*   nbr    = (const int*)d_in[4];     // [27, N]
    float* out = (float*)d_out;                    // [N, 64]

    // ws layout: [0,512) stats; [512, 512+229376) WtF bf16 frag-order (28 slices,
    // slice 27 zero-pad); then featsB bf16 [N][64]
    float* stats = (float*)d_ws;
    unsigned short* WtF    = (unsigned short*)((char*)d_ws + 512);
    unsigned short* featsB = (unsigned short*)((char*)d_ws + 512 + 229376);

    prep<<<436 + 1000, 256, 0, stream>>>(weight, WtF, feats, featsB, stats);
    conv_mfma<<<NVOX / 64, 256, 0, stream>>>(featsB, WtF, nbr, out, stats);
    bn_relu<<<960, 256, 0, stream>>>(out, stats, gamma, beta);
}

// Round 8
// 156.535 us; speedup vs baseline: 1.1256x; 1.0672x over previous
//
#include <hip/hip_runtime.h>

#define NVOX 120000
#define KVOL 27
#define CH 64
#define TOTAL (NVOX * CH)
#define NF4 (TOTAL / 4)
#define EPSV 1e-5f

typedef __attribute__((ext_vector_type(8))) short bf16x8;
typedef __attribute__((ext_vector_type(4))) float f32x4;

__device__ __forceinline__ unsigned short f2bf(float f) {
    unsigned int u = __builtin_bit_cast(unsigned int, f);
    u += 0x7FFFu + ((u >> 16) & 1u);          // RNE
    return (unsigned short)(u >> 16);
}

// ---- prep ------------------------------------------------------------------
// b <  432 : weight fp32 [k][c][d] -> bf16 MFMA-fragment order
//            wtf[((k*8 + grp)*64 + lane)*8 + j], grp=(d>>4)*2+(c>>5),
//            lane=((c&31)>>3)*16+(d&15), j=c&7
// b >= 432 : feats fp32 -> bf16, grid-stride float4
__global__ void prep(const float* __restrict__ w, unsigned short* __restrict__ wtf,
                     const float* __restrict__ f, unsigned short* __restrict__ fb,
                     float* __restrict__ stats) {
    const int b = blockIdx.x;
    const int tid = threadIdx.x;
    if (b < 432) {
        const int t = b * 256 + tid;               // t = k*4096 + c*64 + d (coalesced read)
        const int d = t & 63, c = (t >> 6) & 63, k = t >> 12;
        const int grp = (d >> 4) * 2 + (c >> 5);
        const int l = ((c & 31) >> 3) * 16 + (d & 15);
        const int j = c & 7;
        wtf[(((size_t)k * 8 + grp) * 64 + l) * 8 + j] = f2bf(w[t]);
        if (b == 0 && tid < 128) stats[tid] = 0.f;
    } else {
        for (int t = (b - 432) * 256 + tid; t < NF4; t += 1000 * 256) {
            const float4 x = ((const float4*)f)[t];
            ushort4 y;
            y.x = f2bf(x.x); y.y = f2bf(x.y); y.z = f2bf(x.z); y.w = f2bf(x.w);
            ((ushort4*)fb)[t] = y;
        }
    }
}

__device__ __forceinline__ void gatherRow(const unsigned short* __restrict__ fb,
                                          int idx, int q, bf16x8& a0, bf16x8& a1) {
    const int safe = idx < 0 ? 0 : idx;
    const unsigned short* row = fb + (size_t)safe * CH + q * 8;
    a0 = *(const bf16x8*)row;
    a1 = *(const bf16x8*)(row + 32);
    if (idx < 0) {
        a0 = (bf16x8)(short)0;
        a1 = (bf16x8)(short)0;
    }
}

// ---- conv: barrier-free gather-GEMM with per-tile sparsity skip ------------
// 32 voxels/wave (2 m-tiles), no LDS in the k-loop, B-frags straight from
// L1/L2 (frag-ordered, lane-contiguous). ~5.7% voxel density => ~39% of
// tile-slices are all-invalid and skip gathers+MFMAs entirely (ballot).
__launch_bounds__(256, 4)
__global__ void conv_mfma(const unsigned short* __restrict__ featsB,
                          const unsigned short* __restrict__ WtF,
                          const int* __restrict__ nbr,
                          float* __restrict__ out,
                          float* __restrict__ stats) {
    __shared__ float lstats[128];
    const int tid = threadIdx.x;
    const int lane = tid & 63;
    const int wave = tid >> 6;
    const int m = lane & 15;
    const int q = lane >> 4;
    const int v0 = blockIdx.x * 128 + wave * 32;
    const int r0 = v0 + m;
    const int r1 = v0 + 16 + m;
    const bool ok0 = r0 < NVOX;
    const bool ok1 = r1 < NVOX;

    f32x4 acc[2][4];
#pragma unroll
    for (int t = 0; t < 2; ++t)
#pragma unroll
        for (int nt = 0; nt < 4; ++nt)
            acc[t][nt] = (f32x4){0.f, 0.f, 0.f, 0.f};
    if (tid < 128) lstats[tid] = 0.f;
    __syncthreads();                                // lstats ready; no more barriers until epilogue

    int i0 = ok0 ? nbr[r0] : -1;
    int i1 = ok1 ? nbr[r1] : -1;

    for (int k = 0; k < KVOL; ++k) {
        const unsigned long long t0m = __ballot(i0 >= 0);
        const unsigned long long t1m = __ballot(i1 >= 0);

        bf16x8 a00, a01, a10, a11;
        if (t0m) gatherRow(featsB, i0, q, a00, a01);
        if (t1m) gatherRow(featsB, i1, q, a10, a11);

        // prefetch next slice's indices while gathers are in flight
        int i0n = -1, i1n = -1;
        if (k + 1 < KVOL) {
            const int* nb = nbr + (size_t)(k + 1) * NVOX;
            i0n = ok0 ? nb[r0] : -1;
            i1n = ok1 ? nb[r1] : -1;
        }

        if (t0m | t1m) {
            const unsigned short* wk = WtF + (size_t)k * 4096 + lane * 8;
            bf16x8 bfr[8];
#pragma unroll
            for (int h = 0; h < 8; ++h)
                bfr[h] = *(const bf16x8*)(wk + h * 512);
            if (t0m) {
#pragma unroll
                for (int nt = 0; nt < 4; ++nt) {
                    acc[0][nt] = __builtin_amdgcn_mfma_f32_16x16x32_bf16(a00, bfr[nt * 2 + 0], acc[0][nt], 0, 0, 0);
                    acc[0][nt] = __builtin_amdgcn_mfma_f32_16x16x32_bf16(a01, bfr[nt * 2 + 1], acc[0][nt], 0, 0, 0);
                }
            }
            if (t1m) {
#pragma unroll
                for (int nt = 0; nt < 4; ++nt) {
                    acc[1][nt] = __builtin_amdgcn_mfma_f32_16x16x32_bf16(a10, bfr[nt * 2 + 0], acc[1][nt], 0, 0, 0);
                    acc[1][nt] = __builtin_amdgcn_mfma_f32_16x16x32_bf16(a11, bfr[nt * 2 + 1], acc[1][nt], 0, 0, 0);
                }
            }
        }
        i0 = i0n;
        i1 = i1n;
    }

    // ---- epilogue: guarded stores + block-reduced BN statistics ----
    // D layout: col = m (channel nt*16+m), row = q*4 + r (voxel within tile)
#pragma unroll
    for (int t = 0; t < 2; ++t) {
        const int rbase = v0 + t * 16 + q * 4;
        float* ob = out + (size_t)rbase * CH + m;
#pragma unroll
        for (int nt = 0; nt < 4; ++nt)
#pragma unroll
            for (int r = 0; r < 4; ++r)
                if (rbase + r < NVOX)
                    ob[(size_t)r * CH + nt * 16] = acc[t][nt][r];
    }

#pragma unroll
    for (int nt = 0; nt < 4; ++nt) {
        float s = 0.f, s2 = 0.f;
#pragma unroll
        for (int t = 0; t < 2; ++t)
#pragma unroll
            for (int r = 0; r < 4; ++r) {
                const float x = acc[t][nt][r];       // masked rows are exactly 0
                s += x;
                s2 = fmaf(x, x, s2);
            }
        s  += __shfl_xor(s, 16);  s  += __shfl_xor(s, 32);
        s2 += __shfl_xor(s2, 16); s2 += __shfl_xor(s2, 32);
        if (lane < 16) {
            atomicAdd(&lstats[nt * 16 + m], s);
            atomicAdd(&lstats[64 + nt * 16 + m], s2);
        }
    }
    __syncthreads();
    if (tid < 128) atomicAdd(&stats[tid], lstats[tid]);
}

// ---- bn_relu: grid-stride with inline finalize -----------------------------
__launch_bounds__(256)
__global__ void bn_relu(float* __restrict__ out, const float* __restrict__ stats,
                        const float* __restrict__ gamma, const float* __restrict__ beta) {
    __shared__ float sb[128];
    const int tid = threadIdx.x;
    if (tid < 64) {
        const float inv_n = 1.0f / (float)NVOX;
        const float mean = stats[tid] * inv_n;
        const float var = stats[64 + tid] * inv_n - mean * mean;
        const float sc = gamma[tid] * rsqrtf(var + EPSV);
        sb[tid] = sc;
        sb[64 + tid] = beta[tid] - mean * sc;
    }
    __syncthreads();
    float4* o4 = (float4*)out;
    for (int e = blockIdx.x * 256 + tid; e < NF4; e += 960 * 256) {
        float4 x = o4[e];
        const int cb = (e & 15) * 4;
        x.x = fmaxf(fmaf(x.x, sb[cb + 0], sb[64 + cb + 0]), 0.f);
        x.y = fmaxf(fmaf(x.y, sb[cb + 1], sb[64 + cb + 1]), 0.f);
        x.z = fmaxf(fmaf(x.z, sb[cb + 2], sb[64 + cb + 2]), 0.f);
        x.w = fmaxf(fmaf(x.w, sb[cb + 3], sb[64 + cb + 3]), 0.f);
        o4[e] = x;
    }
}

extern "C" void kernel_launch(void* const* d_in, const int* in_sizes, int n_in,
                              void* d_out, int out_size, void* d_ws, size_t ws_size,
                              hipStream_t stream) {
    const float* feats  = (const float*)d_in[0];   // [N, 64]
    const float* weight = (const float*)d_in[1];   // [27, 64, 64]
    const float* gamma  = (const float*)d_in[2];   // [64]
    const float* beta   = (const float*)d_in[3];   // [64]
    const int*   nbr    = (const int*)d_in[4];     // [27, N]
    float* out = (float*)d_out;                    // [N, 64]

    // ws layout: [0,512) stats; [512, 512+221184) WtF bf16 frag-order; then featsB
    float* stats = (float*)d_ws;
    unsigned short* WtF    = (unsigned short*)((char*)d_ws + 512);
    unsigned short* featsB = (unsigned short*)((char*)d_ws + 512 + 221184);

    prep<<<432 + 1000, 256, 0, stream>>>(weight, WtF, feats, featsB, stats);
    conv_mfma<<<(NVOX + 127) / 128, 256, 0, stream>>>(featsB, WtF, nbr, out, stats);
    bn_relu<<<960, 256, 0, stream>>>(out, stats, gamma, beta);
}

// Round 10
// 154.168 us; speedup vs baseline: 1.1429x; 1.0154x over previous
//
#include <hip/hip_runtime.h>

#define NVOX 120000
#define KVOL 27
#define CH 64
#define TOTAL (NVOX * CH)
#define NF4 (TOTAL / 4)
#define EPSV 1e-5f

typedef __attribute__((ext_vector_type(8))) short bf16x8;
typedef __attribute__((ext_vector_type(4))) float f32x4;

__device__ __forceinline__ unsigned short f2bf(float f) {
    unsigned int u = __builtin_bit_cast(unsigned int, f);
    u += 0x7FFFu + ((u >> 16) & 1u);          // RNE
    return (unsigned short)(u >> 16);
}

// ---- prep: weights only ----------------------------------------------------
// weight fp32 [k][c][d] -> bf16 MFMA-fragment order:
//   wtf[((k*8 + grp)*64 + lane)*8 + j], grp=(d>>4)*2+(c>>5),
//   lane=((c&31)>>3)*16+(d&15), j=c&7   (validated rounds 4-8)
__global__ void prep(const float* __restrict__ w, unsigned short* __restrict__ wtf,
                     float* __restrict__ stats) {
    const int b = blockIdx.x;
    const int tid = threadIdx.x;
    const int t = b * 256 + tid;               // t = k*4096 + c*64 + d (coalesced read)
    const int d = t & 63, c = (t >> 6) & 63, k = t >> 12;
    const int grp = (d >> 4) * 2 + (c >> 5);
    const int l = ((c & 31) >> 3) * 16 + (d & 15);
    const int j = c & 7;
    wtf[(((size_t)k * 8 + grp) * 64 + l) * 8 + j] = f2bf(w[t]);
    if (b == 0 && tid < 128) stats[tid] = 0.f;
}

// gather one fp32 feature row -> two bf16x8 fragments (in-register cvt)
__device__ __forceinline__ void gatherRowF(const float* __restrict__ f,
                                           int idx, int q, bf16x8& a0, bf16x8& a1) {
    const int safe = idx < 0 ? 0 : idx;
    const float* row = f + (size_t)safe * CH + q * 8;
    const float4 p0 = *(const float4*)(row);
    const float4 p1 = *(const float4*)(row + 4);
    const float4 p2 = *(const float4*)(row + 32);
    const float4 p3 = *(const float4*)(row + 36);
    a0 = (bf16x8){(short)f2bf(p0.x), (short)f2bf(p0.y), (short)f2bf(p0.z), (short)f2bf(p0.w),
                  (short)f2bf(p1.x), (short)f2bf(p1.y), (short)f2bf(p1.z), (short)f2bf(p1.w)};
    a1 = (bf16x8){(short)f2bf(p2.x), (short)f2bf(p2.y), (short)f2bf(p2.z), (short)f2bf(p2.w),
                  (short)f2bf(p3.x), (short)f2bf(p3.y), (short)f2bf(p3.z), (short)f2bf(p3.w)};
    if (idx < 0) {
        a0 = (bf16x8)(short)0;
        a1 = (bf16x8)(short)0;
    }
}

// ---- conv: barrier-free, 48 voxels/wave (3 m-tiles), per-tile skip ---------
// fp32 direct gather (no featsB pass); depth-2 A pipeline: gather slice k+1
// while computing slice k; idx prefetched 2 ahead. 625 blocks * 192 = 120000.
__launch_bounds__(256, 3)
__global__ void conv_mfma(const float* __restrict__ feats,
                          const unsigned short* __restrict__ WtF,
                          const int* __restrict__ nbr,
                          float* __restrict__ out,
                          float* __restrict__ stats) {
    __shared__ float lstats[128];
    const int tid = threadIdx.x;
    const int lane = tid & 63;
    const int m = lane & 15;
    const int q = lane >> 4;
    const int v0 = blockIdx.x * 192 + (tid >> 6) * 48;
    const int r[3] = {v0 + m, v0 + 16 + m, v0 + 32 + m};

    f32x4 acc[3][4];
#pragma unroll
    for (int t = 0; t < 3; ++t)
#pragma unroll
        for (int nt = 0; nt < 4; ++nt)
            acc[t][nt] = (f32x4){0.f, 0.f, 0.f, 0.f};
    if (tid < 128) lstats[tid] = 0.f;
    __syncthreads();                                // lstats ready; no more barriers until epilogue

    // prologue: slice-0 gather, slice-1 indices
    bf16x8 a[3][2];
    unsigned long long msk[3];
    int idxn[3];
#pragma unroll
    for (int t = 0; t < 3; ++t) {
        const int i = nbr[r[t]];
        msk[t] = __ballot(i >= 0);
        if (msk[t]) gatherRowF(feats, i, q, a[t][0], a[t][1]);
        else { a[t][0] = (bf16x8)(short)0; a[t][1] = (bf16x8)(short)0; }
        idxn[t] = nbr[NVOX + r[t]];
    }

    for (int k = 0; k < KVOL; ++k) {
        // masks + gathers for slice k+1 (covered by this iteration's compute)
        unsigned long long mn[3];
        bf16x8 an[3][2];
#pragma unroll
        for (int t = 0; t < 3; ++t) {
            mn[t] = __ballot(idxn[t] >= 0);
            if (mn[t]) gatherRowF(feats, idxn[t], q, an[t][0], an[t][1]);
        }
        // prefetch indices for slice k+2
        int idxf[3] = {-1, -1, -1};
        if (k + 2 < KVOL) {
            const int* nb = nbr + (size_t)(k + 2) * NVOX;
#pragma unroll
            for (int t = 0; t < 3; ++t) idxf[t] = nb[r[t]];
        }

        // compute slice k
        if (msk[0] | msk[1] | msk[2]) {
            const unsigned short* wk = WtF + (size_t)k * 4096 + lane * 8;
            bf16x8 bfr[8];
#pragma unroll
            for (int h = 0; h < 8; ++h)
                bfr[h] = *(const bf16x8*)(wk + h * 512);
#pragma unroll
            for (int t = 0; t < 3; ++t) {
                if (msk[t]) {
#pragma unroll
                    for (int nt = 0; nt < 4; ++nt) {
                        acc[t][nt] = __builtin_amdgcn_mfma_f32_16x16x32_bf16(a[t][0], bfr[nt * 2 + 0], acc[t][nt], 0, 0, 0);
                        acc[t][nt] = __builtin_amdgcn_mfma_f32_16x16x32_bf16(a[t][1], bfr[nt * 2 + 1], acc[t][nt], 0, 0, 0);
                    }
                }
            }
        }

        // shift pipeline
#pragma unroll
        for (int t = 0; t < 3; ++t) {
            a[t][0] = an[t][0];
            a[t][1] = an[t][1];
            msk[t] = mn[t];
            idxn[t] = idxf[t];
        }
    }

    // ---- epilogue: stores + block-reduced BN statistics ----
    // D layout: col = m (channel nt*16+m), row = q*4 + rr (voxel within tile)
#pragma unroll
    for (int t = 0; t < 3; ++t) {
        float* ob = out + (size_t)(v0 + t * 16 + q * 4) * CH + m;
#pragma unroll
        for (int nt = 0; nt < 4; ++nt)
#pragma unroll
            for (int rr = 0; rr < 4; ++rr)
                ob[(size_t)rr * CH + nt * 16] = acc[t][nt][rr];
    }

#pragma unroll
    for (int nt = 0; nt < 4; ++nt) {
        float s = 0.f, s2 = 0.f;
#pragma unroll
        for (int t = 0; t < 3; ++t)
#pragma unroll
            for (int rr = 0; rr < 4; ++rr) {
                const float x = acc[t][nt][rr];
                s += x;
                s2 = fmaf(x, x, s2);
            }
        s  += __shfl_xor(s, 16);  s  += __shfl_xor(s, 32);
        s2 += __shfl_xor(s2, 16); s2 += __shfl_xor(s2, 32);
        if (lane < 16) {
            atomicAdd(&lstats[nt * 16 + m], s);
            atomicAdd(&lstats[64 + nt * 16 + m], s2);
        }
    }
    __syncthreads();
    if (tid < 128) atomicAdd(&stats[tid], lstats[tid]);
}

// ---- bn_relu: grid-stride with inline finalize -----------------------------
__launch_bounds__(256)
__global__ void bn_relu(float* __restrict__ out, const float* __restrict__ stats,
                        const float* __restrict__ gamma, const float* __restrict__ beta) {
    __shared__ float sb[128];
    const int tid = threadIdx.x;
    if (tid < 64) {
        const float inv_n = 1.0f / (float)NVOX;
        const float mean = stats[tid] * inv_n;
        const float var = stats[64 + tid] * inv_n - mean * mean;
        const float sc = gamma[tid] * rsqrtf(var + EPSV);
        sb[tid] = sc;
        sb[64 + tid] = beta[tid] - mean * sc;
    }
    __syncthreads();
    float4* o4 = (float4*)out;
    for (int e = blockIdx.x * 256 + tid; e < NF4; e += 960 * 256) {
        float4 x = o4[e];
        const int cb = (e & 15) * 4;
        x.x = fmaxf(fmaf(x.x, sb[cb + 0], sb[64 + cb + 0]), 0.f);
        x.y = fmaxf(fmaf(x.y, sb[cb + 1], sb[64 + cb + 1]), 0.f);
        x.z = fmaxf(fmaf(x.z, sb[cb + 2], sb[64 + cb + 2]), 0.f);
        x.w = fmaxf(fmaf(x.w, sb[cb + 3], sb[64 + cb + 3]), 0.f);
        o4[e] = x;
    }
}

extern "C" void kernel_launch(void* const* d_in, const int* in_sizes, int n_in,
                              void* d_out, int out_size, void* d_ws, size_t ws_size,
                              hipStream_t stream) {
    const float* feats  = (const float*)d_in[0];   // [N, 64]
    const float* weight = (const float*)d_in[1];   // [27, 64, 64]
    const float* gamma  = (const float*)d_in[2];   // [64]
    const float* beta   = (const float*)d_in[3];   // [64]
    const int*   nbr    = (const int*)d_in[4];     // [27, N]
    float* out = (float*)d_out;                    // [N, 64]

    // ws layout: [0,512) stats; [512, 512+221184) WtF bf16 frag-order
    float* stats = (float*)d_ws;
    unsigned short* WtF = (unsigned short*)((char*)d_ws + 512);

    prep<<<432, 256, 0, stream>>>(weight, WtF, stats);
    conv_mfma<<<NVOX / 192, 256, 0, stream>>>(feats, WtF, nbr, out, stats);
    bn_relu<<<960, 256, 0, stream>>>(out, stats, gamma, beta);
}